// Round 21
// baseline (511.540 us; speedup 1.0000x reference)
//
#include <hip/hip_runtime.h>
#include <hip/hip_bf16.h>
#include <stdint.h>

typedef __hip_bfloat16 bf16;
typedef __attribute__((ext_vector_type(8))) short short8;
typedef __attribute__((ext_vector_type(4))) float float4v;
__device__ __forceinline__ float bf(const bf16 x){ return __bfloat162float(x); }
__device__ __forceinline__ float bfu(uint32_t u){ u <<= 16; return __uint_as_float(u); }
__device__ __forceinline__ unsigned short f2bs(float v){
    bf16 b = __float2bfloat16(v);
    return *(unsigned short*)&b;
}

#define FEAT    32
#define HID     64
#define HEADS   6
#define HC      384
#define NLAYERS 4
#define NG      16
#define NP      1000
#define NN      16000   // NG*NP
#define EPS_BN  1e-5f
#define EPS_IN  1e-5f
#define LOG2E   1.44269504f
#define STATSZ  (2*NG*HID)     // per-layer stats: [sum | sumsq][NG][HID]
#define NBLK    (NN/4)         // agg blocks (4 nodes each)
#define NTILES  48             // 768 cols / 16
#define WPKSZ   (NLAYERS*NTILES*64*16)   // shorts

// normalize v (channel c, graph g); st==null -> identity
__device__ __forceinline__ float normv(float v, const float* st, int g, int c){
    if (!st) return v;
    float s  = st[g*HID + c];
    float s2 = st[NG*HID + g*HID + c];
    float mean = s*(1.f/NP);
    float var  = fmaxf(s2*(1.f/NP) - mean*mean, 0.f);
    return (v - mean)*rsqrtf(var + EPS_IN);
}

// ---------------------------------------------------------------------------
__global__ void sentinel_kernel(float* out, int n, float val){
    int i = blockIdx.x*256 + threadIdx.x;
    if (i < n) out[i] = val;
}

// zero meta[64..64+n) in blocks 0..G-2; last block detects int64 edge mode -> meta[0]
__global__ void zero_detect_kernel(int* meta, int n, const int* ei){
    if ((int)blockIdx.x == (int)gridDim.x - 1){
        __shared__ int nz;
        if (threadIdx.x == 0) nz = 0;
        __syncthreads();
        for (int i = 1 + 2*threadIdx.x; i < 1024; i += 512)
            if (ei[i] != 0) atomicAdd(&nz, 1);
        __syncthreads();
        if (threadIdx.x == 0) meta[0] = (nz == 0) ? 1 : 0;
    } else {
        int i = blockIdx.x*256 + threadIdx.x;
        if (i < n) meta[64 + i] = 0;
    }
}

__device__ __forceinline__ int load_idx(const int* ei, int idx, int mode){
    if (mode) return (int)((const long long*)ei)[idx];
    return ei[idx];
}

// ---------------------------------------------------------------------------
__global__ void count_kernel(const int* ei, const int* mode, int* deg, int E){
    int e = blockIdx.x*256 + threadIdx.x;
    if (e >= E) return;
    int d = load_idx(ei, E + e, *mode);
    if (d >= 0 && d < NN) atomicAdd(&deg[d], 1);
}

// ---------------------------------------------------------------------------
// Parallel LDS scan (Hillis-Steele over 256 per-thread partials)
__global__ void scan_kernel(const int* deg, int* rowptr, int N){
    __shared__ int part[256];
    int t = threadIdx.x;
    int chunk = (N + 255)/256;
    int lo = t*chunk, hi = lo + chunk; if (hi > N) hi = N;
    int s = 0;
    for (int i = lo; i < hi; i++) s += deg[i];
    part[t] = s;
    __syncthreads();
    #pragma unroll
    for (int off = 1; off < 256; off <<= 1){
        int v = (t >= off) ? part[t - off] : 0;
        __syncthreads();
        part[t] += v;
        __syncthreads();
    }
    if (t == 255) rowptr[N] = part[255];
    int r = (t == 0) ? 0 : part[t - 1];
    for (int i = lo; i < hi; i++){ rowptr[i] = r; r += deg[i]; }
}

// ---------------------------------------------------------------------------
__global__ void scatter_ea_kernel(const int* ei, const float* pos,
                                  const float* w_e1, const float* b_e1,
                                  const float* w_e2, const float* b_e2,
                                  const int* rowptr, int* fill, const int* mode_p,
                                  int* csr_src, float* ea_csr, int E){
    int e = blockIdx.x*256 + threadIdx.x;
    if (e >= E) return;
    int mode = *mode_p;
    int s = load_idx(ei, e, mode);
    int d = load_idx(ei, E + e, mode);
    if (s < 0 || s >= NN || d < 0 || d >= NN) return;
    float dx = pos[s*3+0] - pos[d*3+0];
    float dy = pos[s*3+1] - pos[d*3+1];
    float dz = pos[s*3+2] - pos[d*3+2];
    float ss = dx*dx + dy*dy + dz*dz;
    float ew = (ss == 0.f) ? 0.f : sqrtf(ss);
    float acc = b_e2[0];
    #pragma unroll
    for (int j = 0; j < 32; j++){
        float m = ew*w_e1[j] + b_e1[j];
        m = m > 0.f ? m : 0.f;
        acc += m*w_e2[j];
    }
    acc = acc > 0.f ? acc : 0.f;
    int p = rowptr[d] + atomicAdd(&fill[d], 1);
    if (p < 0 || p >= E) return;
    csr_src[p] = s;
    ea_csr[p] = acc;
}

// ---------------------------------------------------------------------------
// lin1 (blocks < nb_lin) + wpack (remaining blocks)
__global__ void lin1_wpack_kernel(const float* __restrict__ x,
                                  const float* __restrict__ w1,
                                  const float* __restrict__ b1,
                                  float* __restrict__ h, int N, int nb_lin,
                                  const float* __restrict__ Wl,
                                  const float* __restrict__ Wr,
                                  short* __restrict__ wpk){
    if ((int)blockIdx.x < nb_lin){
        int tid = blockIdx.x*256 + threadIdx.x;
        if (tid >= N*HID) return;
        int n = tid >> 6, c = tid & 63;
        float acc = b1[c];
        #pragma unroll
        for (int k = 0; k < FEAT; k++) acc += x[n*FEAT+k] * w1[k*HID+c];
        h[tid] = acc;
    } else {
        int idx = (blockIdx.x - nb_lin)*256 + threadIdx.x;
        if (idx >= NLAYERS*NTILES*64) return;
        int layer = idx / (NTILES*64);
        int r = idx - layer*NTILES*64;
        int t = r >> 6, lane = r & 63;
        int q = lane >> 4, m = lane & 15;
        int col = t*16 + m;
        bool isR = col >= HC;
        int c2 = isR ? col - HC : col;
        const float* W = (isR ? Wr : Wl) + (size_t)layer*HID*HC;
        unsigned short out[16];
        #pragma unroll
        for (int s = 0; s < 2; s++)
            #pragma unroll
            for (int j = 0; j < 8; j++)
                out[s*8+j] = f2bs(W[(size_t)(s*32 + q*8 + j)*HC + c2]);
        short8* dst = (short8*)(wpk + (size_t)idx*16);
        dst[0] = *(short8*)&out[0];
        dst[1] = *(short8*)&out[8];
    }
}

// ---------------------------------------------------------------------------
// MFMA xlxr with pre-packed B-fragments; direct stores.
__global__ __launch_bounds__(256) void xlxr_mfma_kernel(
        const float* __restrict__ h, const float* __restrict__ statPrev,
        const short* __restrict__ wpk,
        const float* __restrict__ bl, const float* __restrict__ br,
        bf16* __restrict__ xl, bf16* __restrict__ xr, int layer){
    int n0 = blockIdx.x*16;
    int wave = threadIdx.x >> 6;
    int lane = threadIdx.x & 63;
    int q = lane >> 4;
    int m = lane & 15;
    int node = n0 + m;
    int g = node / NP;

    short8 afrag[2];
    #pragma unroll
    for (int s = 0; s < 2; s++){
        const float4* hp4 = (const float4*)(h + (size_t)node*HID + s*32 + q*8);
        float4 va = hp4[0], vb = hp4[1];
        int cb = s*32 + q*8;
        afrag[s][0] = (short)f2bs(normv(va.x, statPrev, g, cb+0));
        afrag[s][1] = (short)f2bs(normv(va.y, statPrev, g, cb+1));
        afrag[s][2] = (short)f2bs(normv(va.z, statPrev, g, cb+2));
        afrag[s][3] = (short)f2bs(normv(va.w, statPrev, g, cb+3));
        afrag[s][4] = (short)f2bs(normv(vb.x, statPrev, g, cb+4));
        afrag[s][5] = (short)f2bs(normv(vb.y, statPrev, g, cb+5));
        afrag[s][6] = (short)f2bs(normv(vb.z, statPrev, g, cb+6));
        afrag[s][7] = (short)f2bs(normv(vb.w, statPrev, g, cb+7));
    }

    const float* blp = bl + (size_t)layer*HC;
    const float* brp = br + (size_t)layer*HC;

    for (int t = wave*12; t < wave*12 + 12; t++){
        const short8* bsrc = (const short8*)(wpk + ((size_t)(layer*NTILES + t)*64 + lane)*16);
        short8 b0 = bsrc[0], b1 = bsrc[1];
        float4v acc = {0.f, 0.f, 0.f, 0.f};
        acc = __builtin_amdgcn_mfma_f32_16x16x32_bf16(afrag[0], b0, acc, 0, 0, 0);
        acc = __builtin_amdgcn_mfma_f32_16x16x32_bf16(afrag[1], b1, acc, 0, 0, 0);
        int col = t*16 + m;
        bool isR = col >= HC;
        int c2 = isR ? col - HC : col;
        float bias = isR ? brp[c2] : blp[c2];
        bf16* dst = isR ? xr : xl;
        #pragma unroll
        for (int r = 0; r < 4; r++){
            int row = q*4 + r;
            dst[(size_t)(n0 + row)*HC + c2] = __float2bfloat16(acc[r] + bias);
        }
    }
}

// ---------------------------------------------------------------------------
// Fused GATv2, 4 waves/block (one node per wave). grp=lane>>3 (grp<6 = one
// head per group), li=lane&7, channels grp*64+li*8..+7. Indices register-
// staged; 3-edge unrolled main loop (one softmax rescale per 3 edges; target
// <=64 VGPR to keep 8 waves/SIMD).
__global__ __launch_bounds__(256) void agg_kernel(
        const bf16* __restrict__ xl, const bf16* __restrict__ xr,
        const int* __restrict__ rowptr,
        const int* __restrict__ csr_src,
        const float* __restrict__ ea_csr,
        const float* __restrict__ We, const float* __restrict__ att,
        const float* __restrict__ b_gat,
        float* __restrict__ h,
        const float* __restrict__ statPrev, float* __restrict__ partial,
        int layer){
    int wave = threadIdx.x >> 6, lane = threadIdx.x & 63;
    int n = blockIdx.x*4 + wave;
    int g = n / NP;
    int r0 = rowptr[n];
    int deg = rowptr[n+1] - r0;

    __shared__ float ps[4][2][HID];

    int grp = lane >> 3, li = lane & 7;
    bool active = grp < HEADS;
    int cb = active ? (grp*HID + li*8) : 0;

    float xrr[8], wer[8], atr[8];
    if (active){
        const uint4* xru = (const uint4*)(xr + (size_t)n*HC);
        uint4 u = xru[grp*8 + li];
        xrr[0]=bfu(u.x&0xffffu); xrr[1]=bfu(u.x>>16);
        xrr[2]=bfu(u.y&0xffffu); xrr[3]=bfu(u.y>>16);
        xrr[4]=bfu(u.z&0xffffu); xrr[5]=bfu(u.z>>16);
        xrr[6]=bfu(u.w&0xffffu); xrr[7]=bfu(u.w>>16);
    }
    #pragma unroll
    for (int i = 0; i < 8; i++){
        wer[i] = We[layer*HC + cb + i];
        atr[i] = att[layer*HC + cb + i]*LOG2E;
    }

    float m_ = -1e30f, l_ = 0.f;
    float acc[8];
    #pragma unroll
    for (int i = 0; i < 8; i++) acc[i] = 0.f;

    const uint4* xlu = (const uint4*)xl;
    int voff = grp*8 + li;

    for (int t0 = 0; t0 < deg; t0 += 64){
        int nch = min(64, deg - t0);
        // coalesced index staging — executed by ALL lanes so every lane's
        // registers are valid shfl sources
        int   sreg = (lane < nch) ? csr_src[r0 + t0 + lane] : 0;
        float ereg = (lane < nch) ? ea_csr[r0 + t0 + lane] : 0.f;
        if (active){
            int j = 0;
            for (; j + 2 < nch; j += 3){
                int sa = __shfl(sreg, j), sb = __shfl(sreg, j + 1), sc = __shfl(sreg, j + 2);
                float eva = __shfl(ereg, j), evb = __shfl(ereg, j + 1), evc = __shfl(ereg, j + 2);
                uint4 ua = xlu[(size_t)sa*48 + voff];
                uint4 ub = xlu[(size_t)sb*48 + voff];
                uint4 uc = xlu[(size_t)sc*48 + voff];
                float xa[8], xb[8], xc[8];
                xa[0]=bfu(ua.x&0xffffu); xa[1]=bfu(ua.x>>16);
                xa[2]=bfu(ua.y&0xffffu); xa[3]=bfu(ua.y>>16);
                xa[4]=bfu(ua.z&0xffffu); xa[5]=bfu(ua.z>>16);
                xa[6]=bfu(ua.w&0xffffu); xa[7]=bfu(ua.w>>16);
                xb[0]=bfu(ub.x&0xffffu); xb[1]=bfu(ub.x>>16);
                xb[2]=bfu(ub.y&0xffffu); xb[3]=bfu(ub.y>>16);
                xb[4]=bfu(ub.z&0xffffu); xb[5]=bfu(ub.z>>16);
                xb[6]=bfu(ub.w&0xffffu); xb[7]=bfu(ub.w>>16);
                xc[0]=bfu(uc.x&0xffffu); xc[1]=bfu(uc.x>>16);
                xc[2]=bfu(uc.y&0xffffu); xc[3]=bfu(uc.y>>16);
                xc[4]=bfu(uc.z&0xffffu); xc[5]=bfu(uc.z>>16);
                xc[6]=bfu(uc.w&0xffffu); xc[7]=bfu(uc.w>>16);
                float ca = 0.f, cbb = 0.f, cc = 0.f;
                #pragma unroll
                for (int i = 0; i < 8; i++){
                    float ga = xa[i] + xrr[i] + eva*wer[i];
                    ga = fmaxf(ga, 0.2f*ga);
                    ca += ga*atr[i];
                    float gb = xb[i] + xrr[i] + evb*wer[i];
                    gb = fmaxf(gb, 0.2f*gb);
                    cbb += gb*atr[i];
                    float gc = xc[i] + xrr[i] + evc*wer[i];
                    gc = fmaxf(gc, 0.2f*gc);
                    cc += gc*atr[i];
                }
                #pragma unroll
                for (int mm = 1; mm <= 4; mm <<= 1){
                    ca  += __shfl_xor(ca, mm);
                    cbb += __shfl_xor(cbb, mm);
                    cc  += __shfl_xor(cc, mm);
                }
                float mn = fmaxf(fmaxf(fmaxf(m_, ca), cbb), cc);
                float r  = exp2f(m_ - mn);
                float pa = exp2f(ca - mn);
                float pb = exp2f(cbb - mn);
                float pc = exp2f(cc - mn);
                l_ = l_*r + pa + pb + pc;
                #pragma unroll
                for (int i = 0; i < 8; i++)
                    acc[i] = acc[i]*r + pa*xa[i] + pb*xb[i] + pc*xc[i];
                m_ = mn;
            }
            for (; j < nch; j++){
                int sa = __shfl(sreg, j);
                float eva = __shfl(ereg, j);
                uint4 ua = xlu[(size_t)sa*48 + voff];
                float xa[8];
                xa[0]=bfu(ua.x&0xffffu); xa[1]=bfu(ua.x>>16);
                xa[2]=bfu(ua.y&0xffffu); xa[3]=bfu(ua.y>>16);
                xa[4]=bfu(ua.z&0xffffu); xa[5]=bfu(ua.z>>16);
                xa[6]=bfu(ua.w&0xffffu); xa[7]=bfu(ua.w>>16);
                float ca = 0.f;
                #pragma unroll
                for (int i = 0; i < 8; i++){
                    float ga = xa[i] + xrr[i] + eva*wer[i];
                    ga = fmaxf(ga, 0.2f*ga);
                    ca += ga*atr[i];
                }
                #pragma unroll
                for (int mm = 1; mm <= 4; mm <<= 1) ca += __shfl_xor(ca, mm);
                float mn = fmaxf(m_, ca);
                float r  = exp2f(m_ - mn);
                float pa = exp2f(ca - mn);
                l_ = l_*r + pa;
                #pragma unroll
                for (int i = 0; i < 8; i++) acc[i] = acc[i]*r + pa*xa[i];
                m_ = mn;
            }
        }
    }

    float v[8];
    float rl = active ? 1.f/(l_ + 1e-16f) : 0.f;
    #pragma unroll
    for (int i = 0; i < 8; i++) v[i] = acc[i]*rl;
    #pragma unroll
    for (int mm = 8; mm <= 32; mm <<= 1)
        #pragma unroll
        for (int i = 0; i < 8; i++) v[i] += __shfl_xor(v[i], mm);

    if (lane < 8){
        int c0 = lane*8;
        const float4* hp4 = (const float4*)(h + (size_t)n*HID + c0);
        float4 h0 = hp4[0], h1 = hp4[1];
        float hv[8] = {h0.x,h0.y,h0.z,h0.w,h1.x,h1.y,h1.z,h1.w};
        float o[8];
        #pragma unroll
        for (int i = 0; i < 8; i++){
            float r = normv(hv[i], statPrev, g, c0+i)
                    + v[i]*(1.f/HEADS) + b_gat[layer*HID + c0 + i];
            o[i] = r > 0.f ? r : 0.f;
            ps[wave][0][c0+i] = o[i];
            ps[wave][1][c0+i] = o[i]*o[i];
        }
        float4* out4 = (float4*)(h + (size_t)n*HID + c0);
        out4[0] = make_float4(o[0],o[1],o[2],o[3]);
        out4[1] = make_float4(o[4],o[5],o[6],o[7]);
    }
    __syncthreads();
    if (threadIdx.x < HID){
        int c = threadIdx.x;
        float s  = ps[0][0][c] + ps[1][0][c] + ps[2][0][c] + ps[3][0][c];
        float s2 = ps[0][1][c] + ps[1][1][c] + ps[2][1][c] + ps[3][1][c];
        partial[(size_t)blockIdx.x*128 + c]      = s;
        partial[(size_t)blockIdx.x*128 + 64 + c] = s2;
    }
}

// ---------------------------------------------------------------------------
// Fold per-block partial stats: 4 lanes per (g,c), shuffle combine.
__global__ void stat_reduce_kernel(const float* __restrict__ partial,
                                   float* __restrict__ stat){
    int idx = blockIdx.x*256 + threadIdx.x;
    if (idx >= NG*HID*4) return;
    int slice = idx & 3;
    int gc = idx >> 2;
    int g = gc >> 6, c = gc & 63;
    int b0 = g*(NP/4);
    float s = 0.f, s2 = 0.f;
    for (int b = slice; b < NP/4; b += 4){
        s  += partial[(size_t)(b0+b)*128 + c];
        s2 += partial[(size_t)(b0+b)*128 + 64 + c];
    }
    s  += __shfl_xor(s, 1);  s  += __shfl_xor(s, 2);
    s2 += __shfl_xor(s2, 1); s2 += __shfl_xor(s2, 2);
    if (slice == 0){
        stat[g*HID + c] = s;
        stat[NG*HID + g*HID + c] = s2;
    }
}

// ---------------------------------------------------------------------------
__global__ __launch_bounds__(256) void final_kernel(
        const float* __restrict__ h, const float* __restrict__ statPrev,
        const float* w1, const float* b1,
        const float* g1, const float* be1, const float* m1, const float* v1,
        const float* w2, const float* b2,
        const float* g2, const float* be2, const float* m2, const float* v2,
        const float* wp, const float* bp,
        float* out, int N){
    int wave = threadIdx.x >> 6, c = threadIdx.x & 63;
    int n = blockIdx.x*4 + wave;
    __shared__ float hr[4][HID], zr[4][HID];
    hr[wave][c] = normv(h[(size_t)n*HID + c], statPrev, n/NP, c);
    __syncthreads();
    float z = b1[c];
    #pragma unroll 8
    for (int k = 0; k < HID; k++) z += hr[wave][k]*w1[k*HID+c];
    z = z > 0.f ? z : 0.f;
    z = (z - m1[c]) / sqrtf(v1[c] + EPS_BN) * g1[c] + be1[c];
    zr[wave][c] = z;
    __syncthreads();
    float ho = b2[c];
    #pragma unroll 8
    for (int k = 0; k < HID; k++) ho += zr[wave][k]*w2[k*HID+c];
    out[(size_t)n*HID + c] = ho;
    float t = (ho - m2[c]) / sqrtf(v2[c] + EPS_BN) * g2[c] + be2[c];
    float p = t * wp[c];
    #pragma unroll
    for (int m = 32; m >= 1; m >>= 1) p += __shfl_xor(p, m);
    if (c == 0) out[(size_t)N*HID + n] = p + bp[0];
}

// ---------------------------------------------------------------------------
extern "C" void kernel_launch(void* const* d_in, const int* in_sizes, int n_in,
                              void* d_out, int out_size, void* d_ws, size_t ws_size,
                              hipStream_t stream){
    const float* x      = (const float*)d_in[0];
    const float* pos    = (const float*)d_in[1];
    const float* w_lin1 = (const float*)d_in[2];
    const float* b_lin1 = (const float*)d_in[3];
    const float* w_e1   = (const float*)d_in[4];
    const float* b_e1   = (const float*)d_in[5];
    const float* w_e2   = (const float*)d_in[6];
    const float* b_e2   = (const float*)d_in[7];
    const float* Wl     = (const float*)d_in[8];
    const float* bl     = (const float*)d_in[9];
    const float* Wr     = (const float*)d_in[10];
    const float* br     = (const float*)d_in[11];
    const float* We     = (const float*)d_in[12];
    const float* att    = (const float*)d_in[13];
    const float* b_gat  = (const float*)d_in[14];
    const float* w_emb1 = (const float*)d_in[15];
    const float* b_emb1 = (const float*)d_in[16];
    const float* bn1_g  = (const float*)d_in[17];
    const float* bn1_b  = (const float*)d_in[18];
    const float* bn1_m  = (const float*)d_in[19];
    const float* bn1_v  = (const float*)d_in[20];
    const float* w_emb2 = (const float*)d_in[21];
    const float* b_emb2 = (const float*)d_in[22];
    const float* bn2_g  = (const float*)d_in[23];
    const float* bn2_b  = (const float*)d_in[24];
    const float* bn2_m  = (const float*)d_in[25];
    const float* bn2_v  = (const float*)d_in[26];
    const float* w_pred = (const float*)d_in[27];
    const float* b_pred = (const float*)d_in[28];
    const int*   ei     = (const int*)d_in[29];

    const int N = in_sizes[0] / FEAT;
    const int E = in_sizes[29] / 2;
    int ob = (out_size + 255)/256;

    bool ok = (n_in >= 32) && (N == NN) && (E > N)
           && (in_sizes[1]  == 3*N)
           && (in_sizes[8]  == NLAYERS*HID*HC)
           && (in_sizes[13] == NLAYERS*HEADS*HID)
           && (in_sizes[27] == HID)
           && (out_size == N*HID + N);
    if (!ok){
        sentinel_kernel<<<ob, 256, 0, stream>>>((float*)d_out, out_size, 4000.0f);
        return;
    }

    char* p = (char*)d_ws;
    auto carve = [&](size_t bytes)->void*{
        void* r = (void*)p;
        p += (bytes + 255) & ~(size_t)255;
        return r;
    };
    int*   meta   = (int*)  carve((size_t)(2*N + 64)*4);
    float* stats  = (float*)carve((size_t)NLAYERS*STATSZ*4);
    float* partial= (float*)carve((size_t)NBLK*128*4);
    short* wpk    = (short*)carve((size_t)WPKSZ*2);
    int*   rowptr = (int*)  carve((size_t)(N+1)*4);
    int*   csr_src= (int*)  carve((size_t)E*4);
    float* ea_csr = (float*)carve((size_t)E*4);
    float* h      = (float*)carve((size_t)N*HID*4);
    bf16*  xl     = (bf16*) carve((size_t)N*HC*2);
    bf16*  xr     = (bf16*) carve((size_t)N*HC*2);
    size_t used = (size_t)(p - (char*)d_ws);

    if (used > ws_size){
        sentinel_kernel<<<ob, 256, 0, stream>>>((float*)d_out, out_size,
                                                5000.0f + (float)(ws_size >> 20));
        return;
    }

    int* mode = meta;
    int* deg  = meta + 64;
    int* fill = meta + 64 + N;

    int zb = (2*N + 255)/256 + 1;
    zero_detect_kernel<<<zb, 256, 0, stream>>>(meta, 2*N, ei);

    int eb = (E + 255)/256;
    count_kernel<<<eb, 256, 0, stream>>>(ei, mode, deg, E);
    scan_kernel<<<1, 256, 0, stream>>>(deg, rowptr, N);
    scatter_ea_kernel<<<eb, 256, 0, stream>>>(ei, pos, w_e1, b_e1, w_e2, b_e2,
                                              rowptr, fill, mode, csr_src, ea_csr, E);

    int nb = (N*HID + 255)/256;
    int wb = (NLAYERS*NTILES*64 + 255)/256;
    lin1_wpack_kernel<<<nb + wb, 256, 0, stream>>>(x, w_lin1, b_lin1, h, N, nb,
                                                   Wl, Wr, wpk);

    for (int l = 0; l < NLAYERS; l++){
        const float* statPrev = (l == 0) ? nullptr : stats + (size_t)(l-1)*STATSZ;
        float* statCur = stats + (size_t)l*STATSZ;
        xlxr_mfma_kernel<<<N/16, 256, 0, stream>>>(h, statPrev, wpk, bl, br,
                                                   xl, xr, l);
        agg_kernel<<<N/4, 256, 0, stream>>>(xl, xr, rowptr, csr_src, ea_csr,
                                            We, att, b_gat, h,
                                            statPrev, partial, l);
        stat_reduce_kernel<<<(NG*HID*4 + 255)/256, 256, 0, stream>>>(partial, statCur);
    }

    final_kernel<<<N/4, 256, 0, stream>>>(h, stats + (size_t)(NLAYERS-1)*STATSZ,
        w_emb1, b_emb1, bn1_g, bn1_b, bn1_m, bn1_v,
        w_emb2, b_emb2, bn2_g, bn2_b, bn2_m, bn2_v,
        w_pred, b_pred, (float*)d_out, N);
}

// Round 22
// 502.338 us; speedup vs baseline: 1.0183x; 1.0183x over previous
//
#include <hip/hip_runtime.h>
#include <hip/hip_bf16.h>
#include <stdint.h>

typedef __hip_bfloat16 bf16;
typedef __attribute__((ext_vector_type(8))) short short8;
typedef __attribute__((ext_vector_type(4))) float float4v;
__device__ __forceinline__ float bf(const bf16 x){ return __bfloat162float(x); }
__device__ __forceinline__ float bfu(uint32_t u){ u <<= 16; return __uint_as_float(u); }
__device__ __forceinline__ unsigned short f2bs(float v){
    bf16 b = __float2bfloat16(v);
    return *(unsigned short*)&b;
}

#define FEAT    32
#define HID     64
#define HEADS   6
#define HC      384
#define NLAYERS 4
#define NG      16
#define NP      1000
#define NN      16000   // NG*NP
#define EPS_BN  1e-5f
#define EPS_IN  1e-5f
#define LOG2E   1.44269504f
#define STATSZ  (2*NG*HID)     // per-layer stats: [sum | sumsq][NG][HID]
#define NBLK    (NN/4)         // agg blocks (4 nodes each)
#define NTILES  48             // 768 cols / 16
#define WPKSZ   (NLAYERS*NTILES*64*16)   // shorts

// normalize v (channel c, graph g); st==null -> identity
__device__ __forceinline__ float normv(float v, const float* st, int g, int c){
    if (!st) return v;
    float s  = st[g*HID + c];
    float s2 = st[NG*HID + g*HID + c];
    float mean = s*(1.f/NP);
    float var  = fmaxf(s2*(1.f/NP) - mean*mean, 0.f);
    return (v - mean)*rsqrtf(var + EPS_IN);
}

// ---------------------------------------------------------------------------
__global__ void sentinel_kernel(float* out, int n, float val){
    int i = blockIdx.x*256 + threadIdx.x;
    if (i < n) out[i] = val;
}

// zero meta[64..64+n) in blocks 0..G-2; last block detects int64 edge mode -> meta[0]
__global__ void zero_detect_kernel(int* meta, int n, const int* ei){
    if ((int)blockIdx.x == (int)gridDim.x - 1){
        __shared__ int nz;
        if (threadIdx.x == 0) nz = 0;
        __syncthreads();
        for (int i = 1 + 2*threadIdx.x; i < 1024; i += 512)
            if (ei[i] != 0) atomicAdd(&nz, 1);
        __syncthreads();
        if (threadIdx.x == 0) meta[0] = (nz == 0) ? 1 : 0;
    } else {
        int i = blockIdx.x*256 + threadIdx.x;
        if (i < n) meta[64 + i] = 0;
    }
}

__device__ __forceinline__ int load_idx(const int* ei, int idx, int mode){
    if (mode) return (int)((const long long*)ei)[idx];
    return ei[idx];
}

// ---------------------------------------------------------------------------
__global__ void count_kernel(const int* ei, const int* mode, int* deg, int E){
    int e = blockIdx.x*256 + threadIdx.x;
    if (e >= E) return;
    int d = load_idx(ei, E + e, *mode);
    if (d >= 0 && d < NN) atomicAdd(&deg[d], 1);
}

// ---------------------------------------------------------------------------
// Parallel LDS scan (Hillis-Steele over 256 per-thread partials)
__global__ void scan_kernel(const int* deg, int* rowptr, int N){
    __shared__ int part[256];
    int t = threadIdx.x;
    int chunk = (N + 255)/256;
    int lo = t*chunk, hi = lo + chunk; if (hi > N) hi = N;
    int s = 0;
    for (int i = lo; i < hi; i++) s += deg[i];
    part[t] = s;
    __syncthreads();
    #pragma unroll
    for (int off = 1; off < 256; off <<= 1){
        int v = (t >= off) ? part[t - off] : 0;
        __syncthreads();
        part[t] += v;
        __syncthreads();
    }
    if (t == 255) rowptr[N] = part[255];
    int r = (t == 0) ? 0 : part[t - 1];
    for (int i = lo; i < hi; i++){ rowptr[i] = r; r += deg[i]; }
}

// ---------------------------------------------------------------------------
__global__ void scatter_ea_kernel(const int* ei, const float* pos,
                                  const float* w_e1, const float* b_e1,
                                  const float* w_e2, const float* b_e2,
                                  const int* rowptr, int* fill, const int* mode_p,
                                  int* csr_src, float* ea_csr, int E){
    int e = blockIdx.x*256 + threadIdx.x;
    if (e >= E) return;
    int mode = *mode_p;
    int s = load_idx(ei, e, mode);
    int d = load_idx(ei, E + e, mode);
    if (s < 0 || s >= NN || d < 0 || d >= NN) return;
    float dx = pos[s*3+0] - pos[d*3+0];
    float dy = pos[s*3+1] - pos[d*3+1];
    float dz = pos[s*3+2] - pos[d*3+2];
    float ss = dx*dx + dy*dy + dz*dz;
    float ew = (ss == 0.f) ? 0.f : sqrtf(ss);
    float acc = b_e2[0];
    #pragma unroll
    for (int j = 0; j < 32; j++){
        float m = ew*w_e1[j] + b_e1[j];
        m = m > 0.f ? m : 0.f;
        acc += m*w_e2[j];
    }
    acc = acc > 0.f ? acc : 0.f;
    int p = rowptr[d] + atomicAdd(&fill[d], 1);
    if (p < 0 || p >= E) return;
    csr_src[p] = s;
    ea_csr[p] = acc;
}

// ---------------------------------------------------------------------------
// lin1 (blocks < nb_lin) + wpack (remaining blocks)
__global__ void lin1_wpack_kernel(const float* __restrict__ x,
                                  const float* __restrict__ w1,
                                  const float* __restrict__ b1,
                                  float* __restrict__ h, int N, int nb_lin,
                                  const float* __restrict__ Wl,
                                  const float* __restrict__ Wr,
                                  short* __restrict__ wpk){
    if ((int)blockIdx.x < nb_lin){
        int tid = blockIdx.x*256 + threadIdx.x;
        if (tid >= N*HID) return;
        int n = tid >> 6, c = tid & 63;
        float acc = b1[c];
        #pragma unroll
        for (int k = 0; k < FEAT; k++) acc += x[n*FEAT+k] * w1[k*HID+c];
        h[tid] = acc;
    } else {
        int idx = (blockIdx.x - nb_lin)*256 + threadIdx.x;
        if (idx >= NLAYERS*NTILES*64) return;
        int layer = idx / (NTILES*64);
        int r = idx - layer*NTILES*64;
        int t = r >> 6, lane = r & 63;
        int q = lane >> 4, m = lane & 15;
        int col = t*16 + m;
        bool isR = col >= HC;
        int c2 = isR ? col - HC : col;
        const float* W = (isR ? Wr : Wl) + (size_t)layer*HID*HC;
        unsigned short out[16];
        #pragma unroll
        for (int s = 0; s < 2; s++)
            #pragma unroll
            for (int j = 0; j < 8; j++)
                out[s*8+j] = f2bs(W[(size_t)(s*32 + q*8 + j)*HC + c2]);
        short8* dst = (short8*)(wpk + (size_t)idx*16);
        dst[0] = *(short8*)&out[0];
        dst[1] = *(short8*)&out[8];
    }
}

// ---------------------------------------------------------------------------
// MFMA xlxr with pre-packed B-fragments; direct stores.
__global__ __launch_bounds__(256) void xlxr_mfma_kernel(
        const float* __restrict__ h, const float* __restrict__ statPrev,
        const short* __restrict__ wpk,
        const float* __restrict__ bl, const float* __restrict__ br,
        bf16* __restrict__ xl, bf16* __restrict__ xr, int layer){
    int n0 = blockIdx.x*16;
    int wave = threadIdx.x >> 6;
    int lane = threadIdx.x & 63;
    int q = lane >> 4;
    int m = lane & 15;
    int node = n0 + m;
    int g = node / NP;

    short8 afrag[2];
    #pragma unroll
    for (int s = 0; s < 2; s++){
        const float4* hp4 = (const float4*)(h + (size_t)node*HID + s*32 + q*8);
        float4 va = hp4[0], vb = hp4[1];
        int cb = s*32 + q*8;
        afrag[s][0] = (short)f2bs(normv(va.x, statPrev, g, cb+0));
        afrag[s][1] = (short)f2bs(normv(va.y, statPrev, g, cb+1));
        afrag[s][2] = (short)f2bs(normv(va.z, statPrev, g, cb+2));
        afrag[s][3] = (short)f2bs(normv(va.w, statPrev, g, cb+3));
        afrag[s][4] = (short)f2bs(normv(vb.x, statPrev, g, cb+4));
        afrag[s][5] = (short)f2bs(normv(vb.y, statPrev, g, cb+5));
        afrag[s][6] = (short)f2bs(normv(vb.z, statPrev, g, cb+6));
        afrag[s][7] = (short)f2bs(normv(vb.w, statPrev, g, cb+7));
    }

    const float* blp = bl + (size_t)layer*HC;
    const float* brp = br + (size_t)layer*HC;

    for (int t = wave*12; t < wave*12 + 12; t++){
        const short8* bsrc = (const short8*)(wpk + ((size_t)(layer*NTILES + t)*64 + lane)*16);
        short8 b0 = bsrc[0], b1 = bsrc[1];
        float4v acc = {0.f, 0.f, 0.f, 0.f};
        acc = __builtin_amdgcn_mfma_f32_16x16x32_bf16(afrag[0], b0, acc, 0, 0, 0);
        acc = __builtin_amdgcn_mfma_f32_16x16x32_bf16(afrag[1], b1, acc, 0, 0, 0);
        int col = t*16 + m;
        bool isR = col >= HC;
        int c2 = isR ? col - HC : col;
        float bias = isR ? brp[c2] : blp[c2];
        bf16* dst = isR ? xr : xl;
        #pragma unroll
        for (int r = 0; r < 4; r++){
            int row = q*4 + r;
            dst[(size_t)(n0 + row)*HC + c2] = __float2bfloat16(acc[r] + bias);
        }
    }
}

// ---------------------------------------------------------------------------
// Fused GATv2, 4 waves/block (one node per wave). grp=lane>>3 (grp<6 = one
// head per group), li=lane&7, channels grp*64+li*8..+7. Indices register-
// staged (one coalesced load per 64-edge chunk, shfl-broadcast in the loop).
// 2-edge unroll. (R18 configuration — measured best, 503 us.)
__global__ __launch_bounds__(256) void agg_kernel(
        const bf16* __restrict__ xl, const bf16* __restrict__ xr,
        const int* __restrict__ rowptr,
        const int* __restrict__ csr_src,
        const float* __restrict__ ea_csr,
        const float* __restrict__ We, const float* __restrict__ att,
        const float* __restrict__ b_gat,
        float* __restrict__ h,
        const float* __restrict__ statPrev, float* __restrict__ partial,
        int layer){
    int wave = threadIdx.x >> 6, lane = threadIdx.x & 63;
    int n = blockIdx.x*4 + wave;
    int g = n / NP;
    int r0 = rowptr[n];
    int deg = rowptr[n+1] - r0;

    __shared__ float ps[4][2][HID];

    int grp = lane >> 3, li = lane & 7;
    bool active = grp < HEADS;
    int cb = active ? (grp*HID + li*8) : 0;

    float xrr[8], wer[8], atr[8];
    if (active){
        const uint4* xru = (const uint4*)(xr + (size_t)n*HC);
        uint4 u = xru[grp*8 + li];
        xrr[0]=bfu(u.x&0xffffu); xrr[1]=bfu(u.x>>16);
        xrr[2]=bfu(u.y&0xffffu); xrr[3]=bfu(u.y>>16);
        xrr[4]=bfu(u.z&0xffffu); xrr[5]=bfu(u.z>>16);
        xrr[6]=bfu(u.w&0xffffu); xrr[7]=bfu(u.w>>16);
    }
    #pragma unroll
    for (int i = 0; i < 8; i++){
        wer[i] = We[layer*HC + cb + i];
        atr[i] = att[layer*HC + cb + i]*LOG2E;
    }

    float m_ = -1e30f, l_ = 0.f;
    float acc[8];
    #pragma unroll
    for (int i = 0; i < 8; i++) acc[i] = 0.f;

    const uint4* xlu = (const uint4*)xl;
    int voff = grp*8 + li;

    for (int t0 = 0; t0 < deg; t0 += 64){
        int nch = min(64, deg - t0);
        // coalesced index staging — executed by ALL lanes so every lane's
        // registers are valid shfl sources
        int   sreg = (lane < nch) ? csr_src[r0 + t0 + lane] : 0;
        float ereg = (lane < nch) ? ea_csr[r0 + t0 + lane] : 0.f;
        if (active){
            int j = 0;
            for (; j + 1 < nch; j += 2){
                int sa = __shfl(sreg, j), sb = __shfl(sreg, j + 1);
                float eva = __shfl(ereg, j), evb = __shfl(ereg, j + 1);
                uint4 ua = xlu[(size_t)sa*48 + voff];
                uint4 ub = xlu[(size_t)sb*48 + voff];
                float xa[8], xb[8];
                xa[0]=bfu(ua.x&0xffffu); xa[1]=bfu(ua.x>>16);
                xa[2]=bfu(ua.y&0xffffu); xa[3]=bfu(ua.y>>16);
                xa[4]=bfu(ua.z&0xffffu); xa[5]=bfu(ua.z>>16);
                xa[6]=bfu(ua.w&0xffffu); xa[7]=bfu(ua.w>>16);
                xb[0]=bfu(ub.x&0xffffu); xb[1]=bfu(ub.x>>16);
                xb[2]=bfu(ub.y&0xffffu); xb[3]=bfu(ub.y>>16);
                xb[4]=bfu(ub.z&0xffffu); xb[5]=bfu(ub.z>>16);
                xb[6]=bfu(ub.w&0xffffu); xb[7]=bfu(ub.w>>16);
                float ca = 0.f, cb_ = 0.f;
                #pragma unroll
                for (int i = 0; i < 8; i++){
                    float ga = xa[i] + xrr[i] + eva*wer[i];
                    ga = fmaxf(ga, 0.2f*ga);
                    ca += ga*atr[i];
                    float gb = xb[i] + xrr[i] + evb*wer[i];
                    gb = fmaxf(gb, 0.2f*gb);
                    cb_ += gb*atr[i];
                }
                #pragma unroll
                for (int mm = 1; mm <= 4; mm <<= 1){
                    ca  += __shfl_xor(ca, mm);
                    cb_ += __shfl_xor(cb_, mm);
                }
                float mn = fmaxf(fmaxf(m_, ca), cb_);
                float r  = exp2f(m_ - mn);
                float pa = exp2f(ca - mn);
                float pb = exp2f(cb_ - mn);
                l_ = l_*r + pa + pb;
                #pragma unroll
                for (int i = 0; i < 8; i++) acc[i] = acc[i]*r + pa*xa[i] + pb*xb[i];
                m_ = mn;
            }
            if (j < nch){
                int sa = __shfl(sreg, j);
                float eva = __shfl(ereg, j);
                uint4 ua = xlu[(size_t)sa*48 + voff];
                float xa[8];
                xa[0]=bfu(ua.x&0xffffu); xa[1]=bfu(ua.x>>16);
                xa[2]=bfu(ua.y&0xffffu); xa[3]=bfu(ua.y>>16);
                xa[4]=bfu(ua.z&0xffffu); xa[5]=bfu(ua.z>>16);
                xa[6]=bfu(ua.w&0xffffu); xa[7]=bfu(ua.w>>16);
                float ca = 0.f;
                #pragma unroll
                for (int i = 0; i < 8; i++){
                    float ga = xa[i] + xrr[i] + eva*wer[i];
                    ga = fmaxf(ga, 0.2f*ga);
                    ca += ga*atr[i];
                }
                #pragma unroll
                for (int mm = 1; mm <= 4; mm <<= 1) ca += __shfl_xor(ca, mm);
                float mn = fmaxf(m_, ca);
                float r  = exp2f(m_ - mn);
                float pa = exp2f(ca - mn);
                l_ = l_*r + pa;
                #pragma unroll
                for (int i = 0; i < 8; i++) acc[i] = acc[i]*r + pa*xa[i];
                m_ = mn;
            }
        }
    }

    float v[8];
    float rl = active ? 1.f/(l_ + 1e-16f) : 0.f;
    #pragma unroll
    for (int i = 0; i < 8; i++) v[i] = acc[i]*rl;
    #pragma unroll
    for (int mm = 8; mm <= 32; mm <<= 1)
        #pragma unroll
        for (int i = 0; i < 8; i++) v[i] += __shfl_xor(v[i], mm);

    if (lane < 8){
        int c0 = lane*8;
        const float4* hp4 = (const float4*)(h + (size_t)n*HID + c0);
        float4 h0 = hp4[0], h1 = hp4[1];
        float hv[8] = {h0.x,h0.y,h0.z,h0.w,h1.x,h1.y,h1.z,h1.w};
        float o[8];
        #pragma unroll
        for (int i = 0; i < 8; i++){
            float r = normv(hv[i], statPrev, g, c0+i)
                    + v[i]*(1.f/HEADS) + b_gat[layer*HID + c0 + i];
            o[i] = r > 0.f ? r : 0.f;
            ps[wave][0][c0+i] = o[i];
            ps[wave][1][c0+i] = o[i]*o[i];
        }
        float4* out4 = (float4*)(h + (size_t)n*HID + c0);
        out4[0] = make_float4(o[0],o[1],o[2],o[3]);
        out4[1] = make_float4(o[4],o[5],o[6],o[7]);
    }
    __syncthreads();
    if (threadIdx.x < HID){
        int c = threadIdx.x;
        float s  = ps[0][0][c] + ps[1][0][c] + ps[2][0][c] + ps[3][0][c];
        float s2 = ps[0][1][c] + ps[1][1][c] + ps[2][1][c] + ps[3][1][c];
        partial[(size_t)blockIdx.x*128 + c]      = s;
        partial[(size_t)blockIdx.x*128 + 64 + c] = s2;
    }
}

// ---------------------------------------------------------------------------
// Fold per-block partial stats: 4 lanes per (g,c), shuffle combine.
__global__ void stat_reduce_kernel(const float* __restrict__ partial,
                                   float* __restrict__ stat){
    int idx = blockIdx.x*256 + threadIdx.x;
    if (idx >= NG*HID*4) return;
    int slice = idx & 3;
    int gc = idx >> 2;
    int g = gc >> 6, c = gc & 63;
    int b0 = g*(NP/4);
    float s = 0.f, s2 = 0.f;
    for (int b = slice; b < NP/4; b += 4){
        s  += partial[(size_t)(b0+b)*128 + c];
        s2 += partial[(size_t)(b0+b)*128 + 64 + c];
    }
    s  += __shfl_xor(s, 1);  s  += __shfl_xor(s, 2);
    s2 += __shfl_xor(s2, 1); s2 += __shfl_xor(s2, 2);
    if (slice == 0){
        stat[g*HID + c] = s;
        stat[NG*HID + g*HID + c] = s2;
    }
}

// ---------------------------------------------------------------------------
__global__ __launch_bounds__(256) void final_kernel(
        const float* __restrict__ h, const float* __restrict__ statPrev,
        const float* w1, const float* b1,
        const float* g1, const float* be1, const float* m1, const float* v1,
        const float* w2, const float* b2,
        const float* g2, const float* be2, const float* m2, const float* v2,
        const float* wp, const float* bp,
        float* out, int N){
    int wave = threadIdx.x >> 6, c = threadIdx.x & 63;
    int n = blockIdx.x*4 + wave;
    __shared__ float hr[4][HID], zr[4][HID];
    hr[wave][c] = normv(h[(size_t)n*HID + c], statPrev, n/NP, c);
    __syncthreads();
    float z = b1[c];
    #pragma unroll 8
    for (int k = 0; k < HID; k++) z += hr[wave][k]*w1[k*HID+c];
    z = z > 0.f ? z : 0.f;
    z = (z - m1[c]) / sqrtf(v1[c] + EPS_BN) * g1[c] + be1[c];
    zr[wave][c] = z;
    __syncthreads();
    float ho = b2[c];
    #pragma unroll 8
    for (int k = 0; k < HID; k++) ho += zr[wave][k]*w2[k*HID+c];
    out[(size_t)n*HID + c] = ho;
    float t = (ho - m2[c]) / sqrtf(v2[c] + EPS_BN) * g2[c] + be2[c];
    float p = t * wp[c];
    #pragma unroll
    for (int m = 32; m >= 1; m >>= 1) p += __shfl_xor(p, m);
    if (c == 0) out[(size_t)N*HID + n] = p + bp[0];
}

// ---------------------------------------------------------------------------
extern "C" void kernel_launch(void* const* d_in, const int* in_sizes, int n_in,
                              void* d_out, int out_size, void* d_ws, size_t ws_size,
                              hipStream_t stream){
    const float* x      = (const float*)d_in[0];
    const float* pos    = (const float*)d_in[1];
    const float* w_lin1 = (const float*)d_in[2];
    const float* b_lin1 = (const float*)d_in[3];
    const float* w_e1   = (const float*)d_in[4];
    const float* b_e1   = (const float*)d_in[5];
    const float* w_e2   = (const float*)d_in[6];
    const float* b_e2   = (const float*)d_in[7];
    const float* Wl     = (const float*)d_in[8];
    const float* bl     = (const float*)d_in[9];
    const float* Wr     = (const float*)d_in[10];
    const float* br     = (const float*)d_in[11];
    const float* We     = (const float*)d_in[12];
    const float* att    = (const float*)d_in[13];
    const float* b_gat  = (const float*)d_in[14];
    const float* w_emb1 = (const float*)d_in[15];
    const float* b_emb1 = (const float*)d_in[16];
    const float* bn1_g  = (const float*)d_in[17];
    const float* bn1_b  = (const float*)d_in[18];
    const float* bn1_m  = (const float*)d_in[19];
    const float* bn1_v  = (const float*)d_in[20];
    const float* w_emb2 = (const float*)d_in[21];
    const float* b_emb2 = (const float*)d_in[22];
    const float* bn2_g  = (const float*)d_in[23];
    const float* bn2_b  = (const float*)d_in[24];
    const float* bn2_m  = (const float*)d_in[25];
    const float* bn2_v  = (const float*)d_in[26];
    const float* w_pred = (const float*)d_in[27];
    const float* b_pred = (const float*)d_in[28];
    const int*   ei     = (const int*)d_in[29];

    const int N = in_sizes[0] / FEAT;
    const int E = in_sizes[29] / 2;
    int ob = (out_size + 255)/256;

    bool ok = (n_in >= 32) && (N == NN) && (E > N)
           && (in_sizes[1]  == 3*N)
           && (in_sizes[8]  == NLAYERS*HID*HC)
           && (in_sizes[13] == NLAYERS*HEADS*HID)
           && (in_sizes[27] == HID)
           && (out_size == N*HID + N);
    if (!ok){
        sentinel_kernel<<<ob, 256, 0, stream>>>((float*)d_out, out_size, 4000.0f);
        return;
    }

    char* p = (char*)d_ws;
    auto carve = [&](size_t bytes)->void*{
        void* r = (void*)p;
        p += (bytes + 255) & ~(size_t)255;
        return r;
    };
    int*   meta   = (int*)  carve((size_t)(2*N + 64)*4);
    float* stats  = (float*)carve((size_t)NLAYERS*STATSZ*4);
    float* partial= (float*)carve((size_t)NBLK*128*4);
    short* wpk    = (short*)carve((size_t)WPKSZ*2);
    int*   rowptr = (int*)  carve((size_t)(N+1)*4);
    int*   csr_src= (int*)  carve((size_t)E*4);
    float* ea_csr = (float*)carve((size_t)E*4);
    float* h      = (float*)carve((size_t)N*HID*4);
    bf16*  xl     = (bf16*) carve((size_t)N*HC*2);
    bf16*  xr     = (bf16*) carve((size_t)N*HC*2);
    size_t used = (size_t)(p - (char*)d_ws);

    if (used > ws_size){
        sentinel_kernel<<<ob, 256, 0, stream>>>((float*)d_out, out_size,
                                                5000.0f + (float)(ws_size >> 20));
        return;
    }

    int* mode = meta;
    int* deg  = meta + 64;
    int* fill = meta + 64 + N;

    int zb = (2*N + 255)/256 + 1;
    zero_detect_kernel<<<zb, 256, 0, stream>>>(meta, 2*N, ei);

    int eb = (E + 255)/256;
    count_kernel<<<eb, 256, 0, stream>>>(ei, mode, deg, E);
    scan_kernel<<<1, 256, 0, stream>>>(deg, rowptr, N);
    scatter_ea_kernel<<<eb, 256, 0, stream>>>(ei, pos, w_e1, b_e1, w_e2, b_e2,
                                              rowptr, fill, mode, csr_src, ea_csr, E);

    int nb = (N*HID + 255)/256;
    int wb = (NLAYERS*NTILES*64 + 255)/256;
    lin1_wpack_kernel<<<nb + wb, 256, 0, stream>>>(x, w_lin1, b_lin1, h, N, nb,
                                                   Wl, Wr, wpk);

    for (int l = 0; l < NLAYERS; l++){
        const float* statPrev = (l == 0) ? nullptr : stats + (size_t)(l-1)*STATSZ;
        float* statCur = stats + (size_t)l*STATSZ;
        xlxr_mfma_kernel<<<N/16, 256, 0, stream>>>(h, statPrev, wpk, bl, br,
                                                   xl, xr, l);
        agg_kernel<<<N/4, 256, 0, stream>>>(xl, xr, rowptr, csr_src, ea_csr,
                                            We, att, b_gat, h,
                                            statPrev, partial, l);
        stat_reduce_kernel<<<(NG*HID*4 + 255)/256, 256, 0, stream>>>(partial, statCur);
    }

    final_kernel<<<N/4, 256, 0, stream>>>(h, stats + (size_t)(NLAYERS-1)*STATSZ,
        w_emb1, b_emb1, bn1_g, bn1_b, bn1_m, bn1_v,
        w_emb2, b_emb2, bn2_g, bn2_b, bn2_m, bn2_v,
        w_pred, b_pred, (float*)d_out, N);
}